// Round 2
// baseline (239.183 us; speedup 1.0000x reference)
//
#include <hip/hip_runtime.h>
#include <hip/hip_fp16.h>
#include <hip/hip_cooperative_groups.h>

namespace cg = cooperative_groups;

#define N_NODES 50000
#define N_EDGES 800000
#define D_FEAT  64
#define BSHIFT  6
#define NBKT    782               // ceil(50000/64)
#define PSHIFT  20
#define SRC_MASK ((1 << PSHIFT) - 1)   // src < 50000 < 2^20
#define CAP     6144              // LDS bucket capacity (avg ~1023, max ~1200)

// cooperative config
#define CNB     391               // blocks; NBKT = 2*CNB exactly
#define CTH     512               // threads/block (8 waves)
#define CCHUNK  2047              // ceil(N_EDGES/CNB); 4 reg slots/thread

// fallback pipeline config
#define NB      256
#define CHUNK   3125              // 256*3125 = 800000

// ---------- workspace layout (ints) — shared by coop + fallback paths ----------
#define WS_TOT    0                            // coop: global claim counters / totals
#define WS_BH     784                          // fallback only [NBKT*NB]
#define WS_PAIR   (WS_BH + NBKT * NB)          // packed (src|dstlow<<20) [N_EDGES]
#define WS_SSRC   (WS_PAIR + N_EDGES)          // overflow sorted src [N_EDGES]
#define WS_PACKED (WS_SSRC + N_EDGES)          // __half2[N_NODES*D_FEAT]
#define WS_INTS   (WS_PACKED + N_NODES * D_FEAT)

__device__ inline void detect_idx_layout(const int* idx, int* flag) {
    // indices < 50000: if stored as int64 LE, every odd 32-bit word is 0.
    int allzero = 1;
    #pragma unroll
    for (int i = 1; i < 129; i += 2) {
        if (idx[i] != 0) allzero = 0;
    }
    *flag = allzero;
}

// tiny pre-kernel: zero the global claim counters
__global__ __launch_bounds__(1024) void zero_gcur(int* __restrict__ W) {
    int t = threadIdx.x;
    if (t < NBKT) W[WS_TOT + t] = 0;
}

// ============================ cooperative mega-kernel ============================
// P0: pack features + stash edges in regs + LDS hist + global slot claim
// sync
// P1: coff prefix (LDS, persists) + scatter stashed edges -> PAIR
// sync
// P2: per bucket (2/block): PAIR->LDS, hist64, scan, LDS counting sort, gather
__global__ __launch_bounds__(CTH, 4) void mega(int* __restrict__ W,
                                               const int* __restrict__ idx,
                                               const float* __restrict__ xs,
                                               const float* __restrict__ xp,
                                               float* __restrict__ out) {
    cg::grid_group gg = cg::this_grid();
    __shared__ int hcur[NBKT];       // hist -> claim base -> scatter cursor
    __shared__ int coff[NBKT + 1];   // bucket base offsets (persists P1->P2)
    __shared__ int pair_l[CAP];
    __shared__ int ssrc_l[CAP];
    __shared__ int h64[64];
    __shared__ int noff[65];
    __shared__ int flg_s;

    const int t = threadIdx.x;
    const int b = blockIdx.x;

    for (int i = t; i < NBKT; i += CTH) hcur[i] = 0;
    if (t == 0) detect_idx_layout(idx, &flg_s);
    __syncthreads();
    const int flg = flg_s;

    // ---- P0a: pack features (fp16 interleaved), vectorized 16B ----
    {
        const float4* xs4 = (const float4*)xs;
        const float4* xp4 = (const float4*)xp;
        uint4* pk4 = (uint4*)(W + WS_PACKED);
        union { __half2 h2; unsigned int u; } c0, c1, c2, c3;
        const int gtid = b * CTH + t;
        for (int g = gtid; g < (N_NODES * D_FEAT) / 4; g += CNB * CTH) {
            float4 a = xs4[g], p = xp4[g];
            c0.h2 = __floats2half2_rn(a.x, p.x);
            c1.h2 = __floats2half2_rn(a.y, p.y);
            c2.h2 = __floats2half2_rn(a.z, p.z);
            c3.h2 = __floats2half2_rn(a.w, p.w);
            pk4[g] = make_uint4(c0.u, c1.u, c2.u, c3.u);
        }
    }

    // ---- P0b: stash this block's edge chunk in registers + LDS hist ----
    const int ebase = b * CCHUNK;
    const int eend  = min(ebase + CCHUNK, N_EDGES);
    int src_r[4], dst_r[4];
    #pragma unroll
    for (int i = 0; i < 4; ++i) {
        int e = ebase + t + i * CTH;
        bool v = (e < eend);
        int s = 0, d = 0;
        if (v) {
            if (flg) {
                int2 sp = ((const int2*)idx)[e];            // int64 src, low word
                int2 dp = ((const int2*)idx)[N_EDGES + e];  // int64 dst, low word
                s = sp.x; d = dp.x;
            } else {
                s = idx[e]; d = idx[N_EDGES + e];
            }
            atomicAdd(&hcur[d >> BSHIFT], 1);
        }
        src_r[i] = v ? s : -1;
        dst_r[i] = d;
    }
    __syncthreads();

    // ---- P0c: claim contiguous within-bucket slot ranges globally ----
    for (int j = t; j < NBKT; j += CTH) {
        int c = hcur[j];
        hcur[j] = (c > 0) ? atomicAdd(&W[WS_TOT + j], c) : 0;
    }

    gg.sync();   // W[WS_TOT+j] == bucket totals; hcur == this block's claim bases

    // ---- P1a: coff = exclusive prefix of totals (wave-0 scan, 13 elems/lane) ----
    for (int j = t; j < NBKT; j += CTH) coff[j] = W[WS_TOT + j];
    __syncthreads();
    if (t < 64) {
        int vals[13];
        int sum = 0;
        const int base = t * 13;
        #pragma unroll
        for (int j2 = 0; j2 < 13; ++j2) {
            int k = base + j2;
            vals[j2] = (k < NBKT) ? coff[k] : 0;
            sum += vals[j2];
        }
        int incl = sum;
        #pragma unroll
        for (int off = 1; off < 64; off <<= 1) {
            int u = __shfl_up(incl, off, 64);
            if (t >= off) incl += u;
        }
        int run = incl - sum;
        #pragma unroll
        for (int j2 = 0; j2 < 13; ++j2) {
            int k = base + j2;
            if (k < NBKT) coff[k] = run;
            run += vals[j2];
        }
    }
    if (t == 0) coff[NBKT] = N_EDGES;
    __syncthreads();
    for (int j = t; j < NBKT; j += CTH) hcur[j] += coff[j];
    __syncthreads();

    // ---- P1b: scatter stashed edges -> PAIR ----
    #pragma unroll
    for (int i = 0; i < 4; ++i) {
        if (src_r[i] >= 0) {
            int d = dst_r[i];
            int pos = atomicAdd(&hcur[d >> BSHIFT], 1);
            W[WS_PAIR + pos] = src_r[i] | ((d & 63) << PSHIFT);
        }
    }

    gg.sync();   // PAIR complete, packed features visible device-wide

    // ---- P2: per-bucket fine sort (LDS) + gather/reduce; buckets 2b, 2b+1 ----
    const __half2* packed = (const __half2*)(W + WS_PACKED);
    const int wave = t >> 6;
    const int lane = t & 63;
    for (int bk = 2 * b; bk < 2 * b + 2; ++bk) {
        const int bbase = coff[bk];
        const int bend  = coff[bk + 1];
        const int nedge = bend - bbase;
        const bool fits = (nedge <= CAP);
        if (t < 64) h64[t] = 0;
        __syncthreads();
        if (fits) {
            for (int e = t; e < nedge; e += CTH) {
                int v = W[WS_PAIR + bbase + e];
                pair_l[e] = v;
                atomicAdd(&h64[(unsigned)v >> PSHIFT], 1);
            }
        } else {
            for (int e = t; e < nedge; e += CTH)
                atomicAdd(&h64[(unsigned)W[WS_PAIR + bbase + e] >> PSHIFT], 1);
        }
        __syncthreads();
        if (t < 64) {
            int c = h64[t];
            int incl = c;
            #pragma unroll
            for (int off = 1; off < 64; off <<= 1) {
                int u = __shfl_up(incl, off, 64);
                if (t >= off) incl += u;
            }
            noff[t] = incl - c;
            if (t == 63) noff[64] = incl;
            h64[t] = incl - c;       // local cursor
        }
        __syncthreads();
        if (fits) {
            for (int e = t; e < nedge; e += CTH) {
                int v = pair_l[e];
                int p = atomicAdd(&h64[(unsigned)v >> PSHIFT], 1);
                ssrc_l[p] = v & SRC_MASK;
            }
        } else {
            for (int e = t; e < nedge; e += CTH) {
                int v = W[WS_PAIR + bbase + e];
                int p = atomicAdd(&h64[(unsigned)v >> PSHIFT], 1);
                W[WS_SSRC + bbase + p] = v & SRC_MASK;
            }
        }
        __syncthreads();

        for (int nn = wave; nn < 64; nn += 8) {
            const int node = (bk << BSHIFT) + nn;
            if (node >= N_NODES) break;     // only bucket 781 tail; nn monotone
            int beg = __builtin_amdgcn_readfirstlane(noff[nn]);
            int end = __builtin_amdgcn_readfirstlane(noff[nn + 1]);

            float s0 = 0.f, s1 = 0.f, s2 = 0.f, s3 = 0.f;
            float s4 = 0.f, s5 = 0.f, s6 = 0.f, s7 = 0.f;
            float p0 = 1.f, p1 = 1.f, p2 = 1.f, p3 = 1.f;
            float p4 = 1.f, p5 = 1.f, p6 = 1.f, p7 = 1.f;
            if (fits) {
                int i = beg;
                for (; i + 7 < end; i += 8) {
                    int a0 = ssrc_l[i],     a1 = ssrc_l[i + 1];
                    int a2 = ssrc_l[i + 2], a3 = ssrc_l[i + 3];
                    int a4 = ssrc_l[i + 4], a5 = ssrc_l[i + 5];
                    int a6 = ssrc_l[i + 6], a7 = ssrc_l[i + 7];
                    float2 f0 = __half22float2(packed[a0 * D_FEAT + lane]);
                    float2 f1 = __half22float2(packed[a1 * D_FEAT + lane]);
                    float2 f2 = __half22float2(packed[a2 * D_FEAT + lane]);
                    float2 f3 = __half22float2(packed[a3 * D_FEAT + lane]);
                    float2 f4 = __half22float2(packed[a4 * D_FEAT + lane]);
                    float2 f5 = __half22float2(packed[a5 * D_FEAT + lane]);
                    float2 f6 = __half22float2(packed[a6 * D_FEAT + lane]);
                    float2 f7 = __half22float2(packed[a7 * D_FEAT + lane]);
                    s0 += f0.x; s1 += f1.x; s2 += f2.x; s3 += f3.x;
                    s4 += f4.x; s5 += f5.x; s6 += f6.x; s7 += f7.x;
                    p0 *= f0.y; p1 *= f1.y; p2 *= f2.y; p3 *= f3.y;
                    p4 *= f4.y; p5 *= f5.y; p6 *= f6.y; p7 *= f7.y;
                }
                for (; i + 1 < end; i += 2) {
                    int a0 = ssrc_l[i], a1 = ssrc_l[i + 1];
                    float2 f0 = __half22float2(packed[a0 * D_FEAT + lane]);
                    float2 f1 = __half22float2(packed[a1 * D_FEAT + lane]);
                    s0 += f0.x; s1 += f1.x;
                    p0 *= f0.y; p1 *= f1.y;
                }
                if (i < end) {
                    float2 f = __half22float2(packed[ssrc_l[i] * D_FEAT + lane]);
                    s0 += f.x;
                    p0 *= f.y;
                }
            } else {
                for (int i = beg; i < end; ++i) {
                    int a = W[WS_SSRC + bbase + i];
                    float2 f = __half22float2(packed[a * D_FEAT + lane]);
                    s0 += f.x;
                    p0 *= f.y;
                }
            }
            float ssum = ((s0 + s1) + (s2 + s3)) + ((s4 + s5) + (s6 + s7));
            float pprd = ((p0 * p1) * (p2 * p3)) * ((p4 * p5) * (p6 * p7));
            out[(long)node * D_FEAT + lane] = ssum;
            out[(long)N_NODES * D_FEAT + (long)node * D_FEAT + lane] = pprd;
        }
        __syncthreads();   // protect h64/pair_l reuse in next bucket iteration
    }
}

// ============================ fallback 4-kernel pipeline ============================
__global__ __launch_bounds__(256) void cast_hist(int* __restrict__ W,
                                                 const int* __restrict__ idx,
                                                 const float* __restrict__ xs,
                                                 const float* __restrict__ xp) {
    __shared__ int h[NBKT];
    __shared__ int flg_s;
    const int t = threadIdx.x;
    for (int i = t; i < NBKT; i += 256) h[i] = 0;
    if (t == 0) detect_idx_layout(idx, &flg_s);
    __syncthreads();
    const float4* xs4 = (const float4*)xs;
    const float4* xp4 = (const float4*)xp;
    uint4* pk4 = (uint4*)(W + WS_PACKED);
    union { __half2 h2; unsigned int u; } c0, c1, c2, c3;
    const int tid = blockIdx.x * 256 + t;
    for (int g = tid; g < (N_NODES * D_FEAT) / 4; g += NB * 256) {
        float4 a = xs4[g], p = xp4[g];
        c0.h2 = __floats2half2_rn(a.x, p.x);
        c1.h2 = __floats2half2_rn(a.y, p.y);
        c2.h2 = __floats2half2_rn(a.z, p.z);
        c3.h2 = __floats2half2_rn(a.w, p.w);
        pk4[g] = make_uint4(c0.u, c1.u, c2.u, c3.u);
    }
    const int flg = flg_s;
    const int base = blockIdx.x * CHUNK;
    for (int e = base + t; e < base + CHUNK; e += 256) {
        int dst = flg ? idx[2 * (N_EDGES + e)] : idx[N_EDGES + e];
        atomicAdd(&h[dst >> BSHIFT], 1);
    }
    __syncthreads();
    for (int i = t; i < NBKT; i += 256)
        W[WS_BH + i * NB + blockIdx.x] = h[i];
}

__global__ __launch_bounds__(256) void bucket_scan(int* __restrict__ W) {
    __shared__ int part[NB];
    int j = blockIdx.x;
    int t = threadIdx.x;
    int c = W[WS_BH + j * NB + t];
    part[t] = c;
    __syncthreads();
    for (int off = 1; off < NB; off <<= 1) {
        int u = (t >= off) ? part[t - off] : 0;
        __syncthreads();
        part[t] += u;
        __syncthreads();
    }
    W[WS_BH + j * NB + t] = part[t] - c;
    if (t == NB - 1) W[WS_TOT + j] = part[t];
}

__global__ __launch_bounds__(256) void coarse_scatter(const int* __restrict__ idx,
                                                      int* __restrict__ W) {
    __shared__ int cur[NBKT];
    __shared__ int flg_s;
    const int t = threadIdx.x;
    for (int i = t; i < NBKT; i += 256) cur[i] = W[WS_TOT + i];
    if (t == 0) detect_idx_layout(idx, &flg_s);
    __syncthreads();
    if (t < 64) {
        int vals[13];
        int sum = 0;
        const int base = t * 13;
        #pragma unroll
        for (int j = 0; j < 13; ++j) {
            int k = base + j;
            vals[j] = (k < NBKT) ? cur[k] : 0;
            sum += vals[j];
        }
        int incl = sum;
        #pragma unroll
        for (int off = 1; off < 64; off <<= 1) {
            int u = __shfl_up(incl, off, 64);
            if (t >= off) incl += u;
        }
        int run = incl - sum;
        #pragma unroll
        for (int j = 0; j < 13; ++j) {
            int k = base + j;
            if (k < NBKT) cur[k] = run;
            run += vals[j];
        }
    }
    __syncthreads();
    for (int i = t; i < NBKT; i += 256) cur[i] += W[WS_BH + i * NB + blockIdx.x];
    __syncthreads();
    const int flg = flg_s;
    const int base = blockIdx.x * CHUNK;
    for (int e = base + t; e < base + CHUNK; e += 256) {
        int src, dst;
        if (flg) { src = idx[2 * e]; dst = idx[2 * (N_EDGES + e)]; }
        else     { src = idx[e];     dst = idx[N_EDGES + e]; }
        int pos = atomicAdd(&cur[dst >> BSHIFT], 1);
        W[WS_PAIR + pos] = src | ((dst & 63) << PSHIFT);
    }
}

__global__ __launch_bounds__(512) void sort_gather(int* __restrict__ W,
                                                   float* __restrict__ out) {
    __shared__ int ssrc_l[CAP];
    __shared__ int red[512];
    __shared__ int h[64];
    __shared__ int noff[65];
    const int b = blockIdx.x;
    const int t = threadIdx.x;
    int part = 0;
    for (int k = t; k < b; k += 512) part += W[WS_TOT + k];
    red[t] = part;
    if (t < 64) h[t] = 0;
    __syncthreads();
    #pragma unroll
    for (int off = 256; off > 0; off >>= 1) {
        if (t < off) red[t] += red[t + off];
        __syncthreads();
    }
    const int bbase = red[0];
    const int bend  = bbase + W[WS_TOT + b];
    const int nedge = bend - bbase;
    for (int e = bbase + t; e < bend; e += 512)
        atomicAdd(&h[(unsigned)W[WS_PAIR + e] >> PSHIFT], 1);
    __syncthreads();
    if (t < 64) {
        int c = h[t];
        int incl = c;
        #pragma unroll
        for (int off = 1; off < 64; off <<= 1) {
            int u = __shfl_up(incl, off, 64);
            if (t >= off) incl += u;
        }
        noff[t] = incl - c;
        if (t == 63) noff[64] = incl;
        h[t] = incl - c;
    }
    __syncthreads();
    const bool fits = (nedge <= CAP);
    if (fits) {
        for (int e = bbase + t; e < bend; e += 512) {
            int v = W[WS_PAIR + e];
            int p = atomicAdd(&h[(unsigned)v >> PSHIFT], 1);
            ssrc_l[p] = v & SRC_MASK;
        }
    } else {
        for (int e = bbase + t; e < bend; e += 512) {
            int v = W[WS_PAIR + e];
            int p = atomicAdd(&h[(unsigned)v >> PSHIFT], 1);
            W[WS_SSRC + bbase + p] = v & SRC_MASK;
        }
    }
    __syncthreads();
    const __half2* packed = (const __half2*)(W + WS_PACKED);
    const int wave = t >> 6;
    const int lane = t & 63;
    for (int nn = wave; nn < 64; nn += 8) {
        const int node = (b << BSHIFT) + nn;
        if (node >= N_NODES) break;
        int beg = __builtin_amdgcn_readfirstlane(noff[nn]);
        int end = __builtin_amdgcn_readfirstlane(noff[nn + 1]);
        float s0 = 0.f, s1 = 0.f, s2 = 0.f, s3 = 0.f;
        float s4 = 0.f, s5 = 0.f, s6 = 0.f, s7 = 0.f;
        float p0 = 1.f, p1 = 1.f, p2 = 1.f, p3 = 1.f;
        float p4 = 1.f, p5 = 1.f, p6 = 1.f, p7 = 1.f;
        if (fits) {
            int i = beg;
            for (; i + 7 < end; i += 8) {
                int a0 = ssrc_l[i],     a1 = ssrc_l[i + 1];
                int a2 = ssrc_l[i + 2], a3 = ssrc_l[i + 3];
                int a4 = ssrc_l[i + 4], a5 = ssrc_l[i + 5];
                int a6 = ssrc_l[i + 6], a7 = ssrc_l[i + 7];
                float2 f0 = __half22float2(packed[a0 * D_FEAT + lane]);
                float2 f1 = __half22float2(packed[a1 * D_FEAT + lane]);
                float2 f2 = __half22float2(packed[a2 * D_FEAT + lane]);
                float2 f3 = __half22float2(packed[a3 * D_FEAT + lane]);
                float2 f4 = __half22float2(packed[a4 * D_FEAT + lane]);
                float2 f5 = __half22float2(packed[a5 * D_FEAT + lane]);
                float2 f6 = __half22float2(packed[a6 * D_FEAT + lane]);
                float2 f7 = __half22float2(packed[a7 * D_FEAT + lane]);
                s0 += f0.x; s1 += f1.x; s2 += f2.x; s3 += f3.x;
                s4 += f4.x; s5 += f5.x; s6 += f6.x; s7 += f7.x;
                p0 *= f0.y; p1 *= f1.y; p2 *= f2.y; p3 *= f3.y;
                p4 *= f4.y; p5 *= f5.y; p6 *= f6.y; p7 *= f7.y;
            }
            for (; i + 1 < end; i += 2) {
                int a0 = ssrc_l[i], a1 = ssrc_l[i + 1];
                float2 f0 = __half22float2(packed[a0 * D_FEAT + lane]);
                float2 f1 = __half22float2(packed[a1 * D_FEAT + lane]);
                s0 += f0.x; s1 += f1.x;
                p0 *= f0.y; p1 *= f1.y;
            }
            if (i < end) {
                float2 f = __half22float2(packed[ssrc_l[i] * D_FEAT + lane]);
                s0 += f.x;
                p0 *= f.y;
            }
        } else {
            for (int i = beg; i < end; ++i) {
                int a = W[WS_SSRC + bbase + i];
                float2 f = __half22float2(packed[a * D_FEAT + lane]);
                s0 += f.x;
                p0 *= f.y;
            }
        }
        float ssum = ((s0 + s1) + (s2 + s3)) + ((s4 + s5) + (s6 + s7));
        float pprd = ((p0 * p1) * (p2 * p3)) * ((p4 * p5) * (p6 * p7));
        out[(long)node * D_FEAT + lane] = ssum;
        out[(long)N_NODES * D_FEAT + (long)node * D_FEAT + lane] = pprd;
    }
}

// ---------------- atomic fallback path, used only if ws is too small ----------------
__device__ inline void atomicMulF32(float* addr, float val) {
    unsigned int* ua = (unsigned int*)addr;
    unsigned int old = __hip_atomic_load(ua, __ATOMIC_RELAXED, __HIP_MEMORY_SCOPE_AGENT);
    while (true) {
        unsigned int assumed = old;
        unsigned int desired = __float_as_uint(__uint_as_float(assumed) * val);
        old = atomicCAS(ua, assumed, desired);
        if (old == assumed) break;
    }
}

__global__ void fb_init(float* __restrict__ out, int* __restrict__ flag,
                        const int* __restrict__ idx) {
    const int n4 = (N_NODES * D_FEAT) / 4;
    int tid = blockIdx.x * blockDim.x + threadIdx.x;
    int stride = gridDim.x * blockDim.x;
    float4* o = (float4*)out;
    const float4 z = make_float4(0.f, 0.f, 0.f, 0.f);
    const float4 one = make_float4(1.f, 1.f, 1.f, 1.f);
    for (int i = tid; i < n4; i += stride) { o[i] = z; o[n4 + i] = one; }
    if (blockIdx.x == 0 && threadIdx.x == 0) detect_idx_layout(idx, flag);
}

__global__ void fb_scatter(const float* __restrict__ xs, const float* __restrict__ xp,
                           const int* __restrict__ idx, float* __restrict__ out,
                           const int* __restrict__ flag) {
    long tid = (long)blockIdx.x * blockDim.x + threadIdx.x;
    const long total = (long)N_EDGES * (D_FEAT / 4);
    if (tid >= total) return;
    int e = (int)(tid >> 4);
    int c = (int)(tid & 15);
    int src, dst;
    if (*flag) { src = idx[2 * e]; dst = idx[2 * (N_EDGES + e)]; }
    else       { src = idx[e];     dst = idx[N_EDGES + e]; }
    const float4 s = ((const float4*)(xs + (long)src * D_FEAT))[c];
    const float4 p = ((const float4*)(xp + (long)src * D_FEAT))[c];
    float* os = out + (long)dst * D_FEAT + c * 4;
    float* op = out + (long)N_NODES * D_FEAT + (long)dst * D_FEAT + c * 4;
    atomicAdd(os + 0, s.x); atomicAdd(os + 1, s.y);
    atomicAdd(os + 2, s.z); atomicAdd(os + 3, s.w);
    atomicMulF32(op + 0, p.x); atomicMulF32(op + 1, p.y);
    atomicMulF32(op + 2, p.z); atomicMulF32(op + 3, p.w);
}

extern "C" void kernel_launch(void* const* d_in, const int* in_sizes, int n_in,
                              void* d_out, int out_size, void* d_ws, size_t ws_size,
                              hipStream_t stream) {
    const float* x_sum  = (const float*)d_in[0];
    const float* x_prod = (const float*)d_in[1];
    const int*   eidx   = (const int*)d_in[2];
    float* out = (float*)d_out;
    int* W = (int*)d_ws;

    if (ws_size < (size_t)WS_INTS * sizeof(int)) {
        fb_init<<<1024, 256, 0, stream>>>(out, W, eidx);
        const long total = (long)N_EDGES * (D_FEAT / 4);
        int grid = (int)((total + 255) / 256);
        fb_scatter<<<grid, 256, 0, stream>>>(x_sum, x_prod, eidx, out, W);
        return;
    }

    zero_gcur<<<1, 1024, 0, stream>>>(W);
    void* args[] = {(void*)&W, (void*)&eidx, (void*)&x_sum, (void*)&x_prod, (void*)&out};
    hipError_t err = hipLaunchCooperativeKernel((const void*)mega, dim3(CNB), dim3(CTH),
                                                args, 0, stream);
    if (err != hipSuccess) {
        // proven 4-kernel pipeline as fallback
        cast_hist<<<NB, 256, 0, stream>>>(W, eidx, x_sum, x_prod);
        bucket_scan<<<NBKT, 256, 0, stream>>>(W);
        coarse_scatter<<<NB, 256, 0, stream>>>(eidx, W);
        sort_gather<<<NBKT, 512, 0, stream>>>(W, out);
    }
}

// Round 3
// 180.142 us; speedup vs baseline: 1.3277x; 1.3277x over previous
//
#include <hip/hip_runtime.h>
#include <hip/hip_fp16.h>

#define N_NODES 50000
#define N_EDGES 800000
#define D_FEAT  64
#define NCAP    64                // slots per node; deg ~ Poisson(16), P(>64) ~ 1e-20

// ---------- workspace layout (ints) ----------
#define WS_NCNT   0                               // per-node degree counters [N_NODES]
#define WS_OVFC   N_NODES                         // overflow counter [1]
#define WS_NSRT   (N_NODES + 16)                  // per-node src slots [N_NODES*NCAP]
#define WS_OVF    (WS_NSRT + N_NODES * NCAP)      // overflow (dst,src) pairs [2*N_EDGES]
#define WS_PACKED (WS_OVF + 2 * N_EDGES)          // __half2[N_NODES*D_FEAT]
#define WS_INTS   (WS_PACKED + N_NODES * D_FEAT)

// K1 config
#define K1_NB 2048
#define K1_TH 256
// K2 config: 4 waves/block, 4 nodes/wave -> 16 nodes/block; 3125*16 = 50000 exactly
#define K2_TH 256
#define NPW   4
#define K2_NB (N_NODES / ((K2_TH / 64) * NPW))

__device__ inline void detect_idx_layout(const int* idx, int* flag) {
    // indices < 50000: if stored as int64 LE, every odd 32-bit word is 0.
    int allzero = 1;
    #pragma unroll
    for (int i = 1; i < 129; i += 2) {
        if (idx[i] != 0) allzero = 0;
    }
    *flag = allzero;
}

// ============ K1: fp16 pack + direct per-node atomic binning ============
__global__ __launch_bounds__(K1_TH) void prep(int* __restrict__ W,
                                              const int* __restrict__ idx,
                                              const float* __restrict__ xs,
                                              const float* __restrict__ xp) {
    __shared__ int flg_s;
    if (threadIdx.x == 0) detect_idx_layout(idx, &flg_s);
    __syncthreads();
    const int flg = flg_s;
    const int tid = blockIdx.x * K1_TH + threadIdx.x;
    const int nthr = K1_NB * K1_TH;

    // pack features: interleave (sum, prod) as half2, 16B vector ops
    const float4* xs4 = (const float4*)xs;
    const float4* xp4 = (const float4*)xp;
    uint4* pk4 = (uint4*)(W + WS_PACKED);
    for (int g = tid; g < (N_NODES * D_FEAT) / 4; g += nthr) {
        float4 a = xs4[g], p = xp4[g];
        union { __half2 h2; unsigned int u; } c0, c1, c2, c3;
        c0.h2 = __floats2half2_rn(a.x, p.x);
        c1.h2 = __floats2half2_rn(a.y, p.y);
        c2.h2 = __floats2half2_rn(a.z, p.z);
        c3.h2 = __floats2half2_rn(a.w, p.w);
        pk4[g] = make_uint4(c0.u, c1.u, c2.u, c3.u);
    }

    // bin edges: one global atomic per edge, scattered 4B src write
    for (int e = tid; e < N_EDGES; e += nthr) {
        int s, d;
        if (flg) {
            s = ((const int2*)idx)[e].x;
            d = ((const int2*)idx)[N_EDGES + e].x;
        } else {
            s = idx[e];
            d = idx[N_EDGES + e];
        }
        int pos = atomicAdd(&W[WS_NCNT + d], 1);
        if (pos < NCAP) {
            W[WS_NSRT + d * NCAP + pos] = s;
        } else {                       // statistically unreachable; full correctness
            int op = atomicAdd(&W[WS_OVFC], 1);
            W[WS_OVF + 2 * op]     = d;
            W[WS_OVF + 2 * op + 1] = s;
        }
    }
}

// ============ K2: per-wave gather/reduce; zero LDS, no barriers ============
__global__ __launch_bounds__(K2_TH) void gather(const int* __restrict__ W,
                                                float* __restrict__ out) {
    const int wave = threadIdx.x >> 6;
    const int lane = threadIdx.x & 63;
    const __half2* packed = (const __half2*)(W + WS_PACKED);
    const int* nsrt = W + WS_NSRT;
    const int nbase = blockIdx.x * ((K2_TH / 64) * NPW) + wave * NPW;

    #pragma unroll
    for (int i = 0; i < NPW; ++i) {
        const int node = nbase + i;          // grid covers [0, N_NODES) exactly
        int cnt = __builtin_amdgcn_readfirstlane(W[WS_NCNT + node]);
        if (cnt > NCAP) cnt = NCAP;          // overflow edges handled in tail
        const int* sp = nsrt + node * NCAP;
        int mysrc = (lane < cnt) ? sp[lane] : 0;   // one coalesced 256B load

        float s0 = 0.f, s1 = 0.f, s2 = 0.f, s3 = 0.f;
        float s4 = 0.f, s5 = 0.f, s6 = 0.f, s7 = 0.f;
        float p0 = 1.f, p1 = 1.f, p2 = 1.f, p3 = 1.f;
        float p4 = 1.f, p5 = 1.f, p6 = 1.f, p7 = 1.f;
        int j = 0;
        for (; j + 7 < cnt; j += 8) {
            int a0 = __shfl(mysrc, j + 0), a1 = __shfl(mysrc, j + 1);
            int a2 = __shfl(mysrc, j + 2), a3 = __shfl(mysrc, j + 3);
            int a4 = __shfl(mysrc, j + 4), a5 = __shfl(mysrc, j + 5);
            int a6 = __shfl(mysrc, j + 6), a7 = __shfl(mysrc, j + 7);
            float2 f0 = __half22float2(packed[a0 * D_FEAT + lane]);
            float2 f1 = __half22float2(packed[a1 * D_FEAT + lane]);
            float2 f2 = __half22float2(packed[a2 * D_FEAT + lane]);
            float2 f3 = __half22float2(packed[a3 * D_FEAT + lane]);
            float2 f4 = __half22float2(packed[a4 * D_FEAT + lane]);
            float2 f5 = __half22float2(packed[a5 * D_FEAT + lane]);
            float2 f6 = __half22float2(packed[a6 * D_FEAT + lane]);
            float2 f7 = __half22float2(packed[a7 * D_FEAT + lane]);
            s0 += f0.x; s1 += f1.x; s2 += f2.x; s3 += f3.x;
            s4 += f4.x; s5 += f5.x; s6 += f6.x; s7 += f7.x;
            p0 *= f0.y; p1 *= f1.y; p2 *= f2.y; p3 *= f3.y;
            p4 *= f4.y; p5 *= f5.y; p6 *= f6.y; p7 *= f7.y;
        }
        for (; j + 1 < cnt; j += 2) {
            int a0 = __shfl(mysrc, j), a1 = __shfl(mysrc, j + 1);
            float2 f0 = __half22float2(packed[a0 * D_FEAT + lane]);
            float2 f1 = __half22float2(packed[a1 * D_FEAT + lane]);
            s0 += f0.x; s1 += f1.x;
            p0 *= f0.y; p1 *= f1.y;
        }
        if (j < cnt) {
            float2 f = __half22float2(packed[__shfl(mysrc, j) * D_FEAT + lane]);
            s0 += f.x;
            p0 *= f.y;
        }
        float ssum = ((s0 + s1) + (s2 + s3)) + ((s4 + s5) + (s6 + s7));
        float pprd = ((p0 * p1) * (p2 * p3)) * ((p4 * p5) * (p6 * p7));
        out[(long)node * D_FEAT + lane] = ssum;
        out[(long)N_NODES * D_FEAT + (long)node * D_FEAT + lane] = pprd;
    }

    // overflow tail (novf == 0 in practice; correct if not)
    int novf = __builtin_amdgcn_readfirstlane(W[WS_OVFC]);
    if (novf > 0) {
        __syncthreads();   // drain this block's out-stores before atomics
        for (int k = wave; k < novf; k += (K2_TH / 64)) {
            int d = W[WS_OVF + 2 * k];
            if (d >= nbase - wave * NPW &&
                d < nbase - wave * NPW + (K2_TH / 64) * NPW) {   // block owns this node
                int s = W[WS_OVF + 2 * k + 1];
                float2 f = __half22float2(packed[s * D_FEAT + lane]);
                float* os = out + (long)d * D_FEAT + lane;
                float* op = out + (long)N_NODES * D_FEAT + (long)d * D_FEAT + lane;
                atomicAdd(os, f.x);
                // CAS multiply
                unsigned int* ua = (unsigned int*)op;
                unsigned int old = __hip_atomic_load(ua, __ATOMIC_RELAXED,
                                                     __HIP_MEMORY_SCOPE_AGENT);
                while (true) {
                    unsigned int assumed = old;
                    unsigned int desired =
                        __float_as_uint(__uint_as_float(assumed) * f.y);
                    old = atomicCAS(ua, assumed, desired);
                    if (old == assumed) break;
                }
            }
        }
    }
}

// ---------------- atomic fallback path, used only if ws is too small ----------------
__device__ inline void atomicMulF32(float* addr, float val) {
    unsigned int* ua = (unsigned int*)addr;
    unsigned int old = __hip_atomic_load(ua, __ATOMIC_RELAXED, __HIP_MEMORY_SCOPE_AGENT);
    while (true) {
        unsigned int assumed = old;
        unsigned int desired = __float_as_uint(__uint_as_float(assumed) * val);
        old = atomicCAS(ua, assumed, desired);
        if (old == assumed) break;
    }
}

__global__ void fb_init(float* __restrict__ out, int* __restrict__ flag,
                        const int* __restrict__ idx) {
    const int n4 = (N_NODES * D_FEAT) / 4;
    int tid = blockIdx.x * blockDim.x + threadIdx.x;
    int stride = gridDim.x * blockDim.x;
    float4* o = (float4*)out;
    const float4 z = make_float4(0.f, 0.f, 0.f, 0.f);
    const float4 one = make_float4(1.f, 1.f, 1.f, 1.f);
    for (int i = tid; i < n4; i += stride) { o[i] = z; o[n4 + i] = one; }
    if (blockIdx.x == 0 && threadIdx.x == 0) detect_idx_layout(idx, flag);
}

__global__ void fb_scatter(const float* __restrict__ xs, const float* __restrict__ xp,
                           const int* __restrict__ idx, float* __restrict__ out,
                           const int* __restrict__ flag) {
    long tid = (long)blockIdx.x * blockDim.x + threadIdx.x;
    const long total = (long)N_EDGES * (D_FEAT / 4);
    if (tid >= total) return;
    int e = (int)(tid >> 4);
    int c = (int)(tid & 15);
    int src, dst;
    if (*flag) { src = idx[2 * e]; dst = idx[2 * (N_EDGES + e)]; }
    else       { src = idx[e];     dst = idx[N_EDGES + e]; }
    const float4 s = ((const float4*)(xs + (long)src * D_FEAT))[c];
    const float4 p = ((const float4*)(xp + (long)src * D_FEAT))[c];
    float* os = out + (long)dst * D_FEAT + c * 4;
    float* op = out + (long)N_NODES * D_FEAT + (long)dst * D_FEAT + c * 4;
    atomicAdd(os + 0, s.x); atomicAdd(os + 1, s.y);
    atomicAdd(os + 2, s.z); atomicAdd(os + 3, s.w);
    atomicMulF32(op + 0, p.x); atomicMulF32(op + 1, p.y);
    atomicMulF32(op + 2, p.z); atomicMulF32(op + 3, p.w);
}

extern "C" void kernel_launch(void* const* d_in, const int* in_sizes, int n_in,
                              void* d_out, int out_size, void* d_ws, size_t ws_size,
                              hipStream_t stream) {
    const float* x_sum  = (const float*)d_in[0];
    const float* x_prod = (const float*)d_in[1];
    const int*   eidx   = (const int*)d_in[2];
    float* out = (float*)d_out;
    int* W = (int*)d_ws;

    if (ws_size < (size_t)WS_INTS * sizeof(int)) {
        fb_init<<<1024, 256, 0, stream>>>(out, W, eidx);
        const long total = (long)N_EDGES * (D_FEAT / 4);
        int grid = (int)((total + 255) / 256);
        fb_scatter<<<grid, 256, 0, stream>>>(x_sum, x_prod, eidx, out, W);
        return;
    }

    // zero NCNT + OVFC (200 KB)
    hipMemsetAsync(W, 0, (size_t)(N_NODES + 1) * sizeof(int), stream);
    prep<<<K1_NB, K1_TH, 0, stream>>>(W, eidx, x_sum, x_prod);
    gather<<<K2_NB, K2_TH, 0, stream>>>(W, out);
}

// Round 4
// 138.149 us; speedup vs baseline: 1.7313x; 1.3040x over previous
//
#include <hip/hip_runtime.h>
#include <hip/hip_fp16.h>

#define N_NODES 50000
#define N_EDGES 800000
#define D_FEAT  64
#define BSHIFT  6
#define NBKT    782               // ceil(50000/64) buckets of 64 nodes
#define PSHIFT  20
#define SRC_MASK ((1 << PSHIFT) - 1)   // src < 50000 < 2^20
#define BCAP    2048              // fixed PAIR slots per bucket; load ~ Poisson(1024)

// K1 config: 391 blocks x 512 threads, 2047 edges/block (391*2047 >= 800000)
#define K1_NB    391
#define K1_TH    512
#define K1_CHUNK 2047
// TOT counters padded to one cacheline to avoid same-line atomic serialization
#define TOTSTRIDE 16

// ---------- workspace layout (ints) ----------
#define WS_TOT    0                               // padded bucket counters [NBKT*16]
#define WS_OVFC   (NBKT * TOTSTRIDE)              // overflow counter [1] (+pad)
#define WS_PAIR   (WS_OVFC + 16)                  // fixed regions [NBKT*BCAP]
#define WS_OVF    (WS_PAIR + NBKT * BCAP)         // overflow (dst,src) [2*N_EDGES]
#define WS_PACKED (WS_OVF + 2 * N_EDGES)          // __half2[N_NODES*D_FEAT]
#define WS_INTS   (WS_PACKED + N_NODES * D_FEAT)

__device__ inline void detect_idx_layout(const int* idx, int* flag) {
    int allzero = 1;
    #pragma unroll
    for (int i = 1; i < 129; i += 2) {
        if (idx[i] != 0) allzero = 0;
    }
    *flag = allzero;
}

// ============ K1: fused pack + hist + claim + clustered scatter ============
__global__ __launch_bounds__(K1_TH) void front(int* __restrict__ W,
                                               const int* __restrict__ idx,
                                               const float* __restrict__ xs,
                                               const float* __restrict__ xp) {
    __shared__ int h[NBKT];          // hist -> claim base -> scatter cursor
    __shared__ int flg_s;
    const int t = threadIdx.x;
    for (int i = t; i < NBKT; i += K1_TH) h[i] = 0;
    if (t == 0) flg_s = 1;
    __syncthreads();
    if (t < 128 && idx[2 * t + 1] != 0) flg_s = 0;   // parallel int64 detect
    __syncthreads();
    const int flg = flg_s;

    // stash this block's edges in registers + LDS bucket hist
    const int ebase = blockIdx.x * K1_CHUNK;
    const int eend  = min(ebase + K1_CHUNK, N_EDGES);
    int src_r[4], dst_r[4];
    #pragma unroll
    for (int i = 0; i < 4; ++i) {
        int e = ebase + t + i * K1_TH;
        bool v = (e < eend);
        int s = 0, d = 0;
        if (v) {
            if (flg) {
                s = ((const int2*)idx)[e].x;
                d = ((const int2*)idx)[N_EDGES + e].x;
            } else {
                s = idx[e];
                d = idx[N_EDGES + e];
            }
            atomicAdd(&h[d >> BSHIFT], 1);
        }
        src_r[i] = v ? s : -1;
        dst_r[i] = d;
    }

    // pack features fp16-interleaved (independent work; overlaps hist latency)
    {
        const float4* xs4 = (const float4*)xs;
        const float4* xp4 = (const float4*)xp;
        uint4* pk4 = (uint4*)(W + WS_PACKED);
        const int gtid = blockIdx.x * K1_TH + t;
        for (int g = gtid; g < (N_NODES * D_FEAT) / 4; g += K1_NB * K1_TH) {
            float4 a = xs4[g], p = xp4[g];
            union { __half2 h2; unsigned int u; } c0, c1, c2, c3;
            c0.h2 = __floats2half2_rn(a.x, p.x);
            c1.h2 = __floats2half2_rn(a.y, p.y);
            c2.h2 = __floats2half2_rn(a.z, p.z);
            c3.h2 = __floats2half2_rn(a.w, p.w);
            pk4[g] = make_uint4(c0.u, c1.u, c2.u, c3.u);
        }
    }
    __syncthreads();

    // claim contiguous within-bucket ranges (padded counters: 1 line each)
    for (int j = t; j < NBKT; j += K1_TH) {
        int c = h[j];
        h[j] = (c > 0) ? atomicAdd(&W[WS_TOT + j * TOTSTRIDE], c) : 0;
    }
    __syncthreads();

    // scatter from regs into fixed bucket regions — clustered writes
    #pragma unroll
    for (int i = 0; i < 4; ++i) {
        if (src_r[i] >= 0) {
            int d = dst_r[i];
            int bkt = d >> BSHIFT;
            int pos = atomicAdd(&h[bkt], 1);
            if (pos < BCAP) {
                W[WS_PAIR + bkt * BCAP + pos] = src_r[i] | ((d & 63) << PSHIFT);
            } else {                 // statistically unreachable; fully correct
                int op = atomicAdd(&W[WS_OVFC], 1);
                W[WS_OVF + 2 * op]     = d;
                W[WS_OVF + 2 * op + 1] = src_r[i];
            }
        }
    }
}

// ============ K2: per-bucket LDS counting sort + gather/reduce ============
__global__ __launch_bounds__(512) void sort_gather(const int* __restrict__ W,
                                                   float* __restrict__ out) {
    __shared__ int pair_l[BCAP];     // 8 KB
    __shared__ int ssrc_l[BCAP];     // 8 KB
    __shared__ int h64[64];
    __shared__ int noff[65];
    const int b = blockIdx.x;
    const int t = threadIdx.x;
    const int nedge = min(W[WS_TOT + b * TOTSTRIDE], BCAP);
    const int pbase = WS_PAIR + b * BCAP;

    if (t < 64) h64[t] = 0;
    __syncthreads();
    for (int e = t; e < nedge; e += 512) {
        int v = W[pbase + e];
        pair_l[e] = v;
        atomicAdd(&h64[(unsigned)v >> PSHIFT], 1);
    }
    __syncthreads();
    if (t < 64) {
        int c = h64[t];
        int incl = c;
        #pragma unroll
        for (int off = 1; off < 64; off <<= 1) {
            int u = __shfl_up(incl, off, 64);
            if (t >= off) incl += u;
        }
        noff[t] = incl - c;
        if (t == 63) noff[64] = incl;
        h64[t] = incl - c;           // local cursor
    }
    __syncthreads();
    for (int e = t; e < nedge; e += 512) {
        int v = pair_l[e];
        int p = atomicAdd(&h64[(unsigned)v >> PSHIFT], 1);
        ssrc_l[p] = v & SRC_MASK;
    }
    __syncthreads();

    const __half2* packed = (const __half2*)(W + WS_PACKED);
    const int wave = t >> 6;
    const int lane = t & 63;
    for (int nn = wave; nn < 64; nn += 8) {
        const int node = (b << BSHIFT) + nn;
        if (node >= N_NODES) break;      // tail of bucket 781 only; nn monotone
        int beg = __builtin_amdgcn_readfirstlane(noff[nn]);
        int end = __builtin_amdgcn_readfirstlane(noff[nn + 1]);

        float s0 = 0.f, s1 = 0.f, s2 = 0.f, s3 = 0.f;
        float s4 = 0.f, s5 = 0.f, s6 = 0.f, s7 = 0.f;
        float p0 = 1.f, p1 = 1.f, p2 = 1.f, p3 = 1.f;
        float p4 = 1.f, p5 = 1.f, p6 = 1.f, p7 = 1.f;
        int i = beg;
        for (; i + 7 < end; i += 8) {
            int a0 = ssrc_l[i],     a1 = ssrc_l[i + 1];
            int a2 = ssrc_l[i + 2], a3 = ssrc_l[i + 3];
            int a4 = ssrc_l[i + 4], a5 = ssrc_l[i + 5];
            int a6 = ssrc_l[i + 6], a7 = ssrc_l[i + 7];
            float2 f0 = __half22float2(packed[a0 * D_FEAT + lane]);
            float2 f1 = __half22float2(packed[a1 * D_FEAT + lane]);
            float2 f2 = __half22float2(packed[a2 * D_FEAT + lane]);
            float2 f3 = __half22float2(packed[a3 * D_FEAT + lane]);
            float2 f4 = __half22float2(packed[a4 * D_FEAT + lane]);
            float2 f5 = __half22float2(packed[a5 * D_FEAT + lane]);
            float2 f6 = __half22float2(packed[a6 * D_FEAT + lane]);
            float2 f7 = __half22float2(packed[a7 * D_FEAT + lane]);
            s0 += f0.x; s1 += f1.x; s2 += f2.x; s3 += f3.x;
            s4 += f4.x; s5 += f5.x; s6 += f6.x; s7 += f7.x;
            p0 *= f0.y; p1 *= f1.y; p2 *= f2.y; p3 *= f3.y;
            p4 *= f4.y; p5 *= f5.y; p6 *= f6.y; p7 *= f7.y;
        }
        for (; i + 1 < end; i += 2) {
            int a0 = ssrc_l[i], a1 = ssrc_l[i + 1];
            float2 f0 = __half22float2(packed[a0 * D_FEAT + lane]);
            float2 f1 = __half22float2(packed[a1 * D_FEAT + lane]);
            s0 += f0.x; s1 += f1.x;
            p0 *= f0.y; p1 *= f1.y;
        }
        if (i < end) {
            float2 f = __half22float2(packed[ssrc_l[i] * D_FEAT + lane]);
            s0 += f.x;
            p0 *= f.y;
        }
        float ssum = ((s0 + s1) + (s2 + s3)) + ((s4 + s5) + (s6 + s7));
        float pprd = ((p0 * p1) * (p2 * p3)) * ((p4 * p5) * (p6 * p7));
        out[(long)node * D_FEAT + lane] = ssum;
        out[(long)N_NODES * D_FEAT + (long)node * D_FEAT + lane] = pprd;
    }

    // overflow tail (empty in practice; correct if not)
    int novf = W[WS_OVFC];
    if (novf > 0) {
        __syncthreads();
        for (int k = wave; k < novf; k += 8) {
            int d = W[WS_OVF + 2 * k];
            if ((d >> BSHIFT) == b) {
                int s = W[WS_OVF + 2 * k + 1];
                float2 f = __half22float2(packed[s * D_FEAT + lane]);
                atomicAdd(out + (long)d * D_FEAT + lane, f.x);
                unsigned int* ua =
                    (unsigned int*)(out + (long)N_NODES * D_FEAT + (long)d * D_FEAT + lane);
                unsigned int old = __hip_atomic_load(ua, __ATOMIC_RELAXED,
                                                     __HIP_MEMORY_SCOPE_AGENT);
                while (true) {
                    unsigned int assumed = old;
                    unsigned int desired =
                        __float_as_uint(__uint_as_float(assumed) * f.y);
                    old = atomicCAS(ua, assumed, desired);
                    if (old == assumed) break;
                }
            }
        }
    }
}

// ---------------- atomic fallback path, used only if ws is too small ----------------
__device__ inline void atomicMulF32(float* addr, float val) {
    unsigned int* ua = (unsigned int*)addr;
    unsigned int old = __hip_atomic_load(ua, __ATOMIC_RELAXED, __HIP_MEMORY_SCOPE_AGENT);
    while (true) {
        unsigned int assumed = old;
        unsigned int desired = __float_as_uint(__uint_as_float(assumed) * val);
        old = atomicCAS(ua, assumed, desired);
        if (old == assumed) break;
    }
}

__global__ void fb_init(float* __restrict__ out, int* __restrict__ flag,
                        const int* __restrict__ idx) {
    const int n4 = (N_NODES * D_FEAT) / 4;
    int tid = blockIdx.x * blockDim.x + threadIdx.x;
    int stride = gridDim.x * blockDim.x;
    float4* o = (float4*)out;
    const float4 z = make_float4(0.f, 0.f, 0.f, 0.f);
    const float4 one = make_float4(1.f, 1.f, 1.f, 1.f);
    for (int i = tid; i < n4; i += stride) { o[i] = z; o[n4 + i] = one; }
    if (blockIdx.x == 0 && threadIdx.x == 0) detect_idx_layout(idx, flag);
}

__global__ void fb_scatter(const float* __restrict__ xs, const float* __restrict__ xp,
                           const int* __restrict__ idx, float* __restrict__ out,
                           const int* __restrict__ flag) {
    long tid = (long)blockIdx.x * blockDim.x + threadIdx.x;
    const long total = (long)N_EDGES * (D_FEAT / 4);
    if (tid >= total) return;
    int e = (int)(tid >> 4);
    int c = (int)(tid & 15);
    int src, dst;
    if (*flag) { src = idx[2 * e]; dst = idx[2 * (N_EDGES + e)]; }
    else       { src = idx[e];     dst = idx[N_EDGES + e]; }
    const float4 s = ((const float4*)(xs + (long)src * D_FEAT))[c];
    const float4 p = ((const float4*)(xp + (long)src * D_FEAT))[c];
    float* os = out + (long)dst * D_FEAT + c * 4;
    float* op = out + (long)N_NODES * D_FEAT + (long)dst * D_FEAT + c * 4;
    atomicAdd(os + 0, s.x); atomicAdd(os + 1, s.y);
    atomicAdd(os + 2, s.z); atomicAdd(os + 3, s.w);
    atomicMulF32(op + 0, p.x); atomicMulF32(op + 1, p.y);
    atomicMulF32(op + 2, p.z); atomicMulF32(op + 3, p.w);
}

extern "C" void kernel_launch(void* const* d_in, const int* in_sizes, int n_in,
                              void* d_out, int out_size, void* d_ws, size_t ws_size,
                              hipStream_t stream) {
    const float* x_sum  = (const float*)d_in[0];
    const float* x_prod = (const float*)d_in[1];
    const int*   eidx   = (const int*)d_in[2];
    float* out = (float*)d_out;
    int* W = (int*)d_ws;

    if (ws_size < (size_t)WS_INTS * sizeof(int)) {
        fb_init<<<1024, 256, 0, stream>>>(out, W, eidx);
        const long total = (long)N_EDGES * (D_FEAT / 4);
        int grid = (int)((total + 255) / 256);
        fb_scatter<<<grid, 256, 0, stream>>>(x_sum, x_prod, eidx, out, W);
        return;
    }

    // zero padded bucket counters + overflow counter (~50 KB)
    hipMemsetAsync(W, 0, (size_t)(WS_OVFC + 16) * sizeof(int), stream);
    front<<<K1_NB, K1_TH, 0, stream>>>(W, eidx, x_sum, x_prod);
    sort_gather<<<NBKT, 512, 0, stream>>>(W, out);
}